// Round 1
// baseline (83.081 us; speedup 1.0000x reference)
//
#include <hip/hip_runtime.h>
#include <math.h>

// Problem constants (from the reference): N=12000, NEI=32, K=8, D=64
#define NPTS 12000
#define NNEI 32
#define KK   8
#define DD   64

// Key insight: every per-(n,m) quantity in the reference depends on the
// neighbor ONLY through j = nei[n,m].  So:
//   Pass A: per point j, compute F[j,:] = x_final row (through softmax+agg+normalize)
//   Pass B: per n, out[n] = lorentz_normalize( sum_m (mask+1e-4) * F[nei[n,m]] )
// This is 32x less arithmetic than the naive N*NEI formulation.

// ---------------------------------------------------------------- prep ----
// km[k][d]   = (kernels * metric)[k][d]  (metric = +1 for d=0, -1 otherwise)
// escale[k]  = exp(scales[k])
__global__ void prep_kernel(const float* __restrict__ kp,
                            const float* __restrict__ scales,
                            float* __restrict__ km,
                            float* __restrict__ escale) {
    int l = threadIdx.x;  // 0..63, one wave
    #pragma unroll
    for (int k = 0; k < KK; ++k) {
        float sp = (l == 0) ? 0.0f : kp[k * DD + l];  // kernel_points[:,0] == 0
        float ss = sp * sp;
        #pragma unroll
        for (int off = 32; off > 0; off >>= 1) ss += __shfl_xor(ss, off);
        float nrm = sqrtf(fmaxf(ss, 1e-8f));          // clip(sum sp^2, 1e-8)
        float val = (l == 0) ? coshf(nrm) : -(sinhf(nrm) / nrm) * sp;
        km[k * DD + l] = val;
    }
    if (l < KK) escale[l] = expf(scales[l]);
}

// ---------------------------------------------------------------- pass A ---
// One wave per point j; lane = output dim o.  4 waves per block share the
// per-k LDS staging of W[k] (16 KB, +1 pad -> conflict-free scalar reads).
__launch_bounds__(256)
__global__ void passA_kernel(const float* __restrict__ x,
                             const float* __restrict__ W,
                             const float* __restrict__ b,
                             const float* __restrict__ km,
                             const float* __restrict__ escale,
                             float* __restrict__ F) {
    __shared__ float wl[DD * 65];  // [o][d] with pad 65: bank = (o+d)%32 -> 2-way (free)

    const int t    = threadIdx.x;
    const int wave = t >> 6;
    const int lane = t & 63;
    const int j    = blockIdx.x * 4 + wave;   // 3000*4 == 12000 exactly

    // x row of this wave's point, held in registers (static indexing only!)
    float xr[DD];
    const float4* xrow4 = (const float4*)(x + (size_t)j * DD);
    #pragma unroll
    for (int i = 0; i < 16; ++i) {
        float4 v = xrow4[i];
        xr[4 * i + 0] = v.x; xr[4 * i + 1] = v.y;
        xr[4 * i + 2] = v.z; xr[4 * i + 3] = v.w;
    }
    const float xlane = x[(size_t)j * DD + lane];  // lane's own element (coalesced)

    // ---- dis[k] = arccosh(clip(<x, km_k>, 1+1e-7)) ; softmax over k ----
    float wk[KK];
    {
        float dis[KK];
        #pragma unroll
        for (int k = 0; k < KK; ++k) {
            float p = xlane * km[k * DD + lane];
            #pragma unroll
            for (int off = 32; off > 0; off >>= 1) p += __shfl_xor(p, off);
            float nc = fmaxf(p, 1.0f + 1e-7f);
            dis[k] = logf(nc + sqrtf(nc * nc - 1.0f));  // arccosh
        }
        float mx = -dis[0];
        #pragma unroll
        for (int k = 1; k < KK; ++k) mx = fmaxf(mx, -dis[k]);
        float sum = 0.0f;
        #pragma unroll
        for (int k = 0; k < KK; ++k) { wk[k] = expf(-dis[k] - mx); sum += wk[k]; }
        float inv = 1.0f / sum;
        #pragma unroll
        for (int k = 0; k < KK; ++k) wk[k] *= inv;
    }

    // preload exp(scales)
    float es[KK];
    #pragma unroll
    for (int k = 0; k < KK; ++k) es[k] = escale[k];

    // ---- main loop over kernels: y row -> x_tr -> weighted accumulate ----
    float agg = 0.0f;
    for (int k = 0; k < KK; ++k) {
        __syncthreads();  // protect wl from previous iteration's readers
        // stage W[k] (64x64 fp32) into LDS, coalesced float4 global loads
        const float4* Wk4 = (const float4*)(W + (size_t)k * DD * DD);
        #pragma unroll
        for (int q = 0; q < 4; ++q) {
            int f4 = q * 256 + t;        // 0..1023
            int o  = f4 >> 4;
            int d4 = f4 & 15;
            float4 v = Wk4[f4];
            float* dst = &wl[o * 65 + d4 * 4];
            dst[0] = v.x; dst[1] = v.y; dst[2] = v.z; dst[3] = v.w;
        }
        __syncthreads();

        // y_o = b[k][o] + sum_d W[k][o][d] * x[d]
        float y = b[k * DD + lane];
        #pragma unroll
        for (int d = 0; d < DD; ++d) y += wl[lane * 65 + d] * xr[d];

        // row stats across lanes: y0 and sum_{o>=1} y^2
        float ysq = (lane == 0) ? 0.0f : y * y;
        #pragma unroll
        for (int off = 32; off > 0; off >>= 1) ysq += __shfl_xor(ysq, off);
        float y0 = __shfl(y, 0);

        float time = es[k] / (1.0f + expf(-y0)) + 1.0001f;   // sigmoid*exp(scale)+1.0001
        float sc   = (time * time - 1.0f) / fmaxf(ysq, 1e-8f);
        float s3   = sqrtf(sc);
        float xtr  = (lane == 0) ? time : y * s3;
        agg += wk[k] * xtr;
    }

    // ---- lorentz normalize: F[j] = agg / sqrt(clip(|<agg,agg>_L|,1e-8)) ----
    float v = (lane == 0) ? -agg * agg : agg * agg;
    #pragma unroll
    for (int off = 32; off > 0; off >>= 1) v += __shfl_xor(v, off);
    float den = sqrtf(fmaxf(fabsf(v), 1e-8f));
    F[(size_t)j * DD + lane] = agg / den;
}

// ---------------------------------------------------------------- pass B ---
// One wave per n: gather 32 F rows (L2-resident), mask-weighted midpoint.
__launch_bounds__(256)
__global__ void passB_kernel(const float* __restrict__ F,
                             const int* __restrict__ nei,
                             const int* __restrict__ mask,
                             float* __restrict__ out) {
    const int t    = threadIdx.x;
    const int wave = t >> 6;
    const int lane = t & 63;
    const int n    = blockIdx.x * 4 + wave;

    float acc = 0.0f;
    #pragma unroll 4
    for (int m = 0; m < NNEI; ++m) {
        int   jm = nei[n * NNEI + m];                 // wave-uniform
        float w  = (float)mask[n * NNEI + m] + 1e-4f; // wave-uniform
        acc += w * F[(size_t)jm * DD + lane];         // coalesced 256B row
    }
    float v = (lane == 0) ? -acc * acc : acc * acc;
    #pragma unroll
    for (int off = 32; off > 0; off >>= 1) v += __shfl_xor(v, off);
    float den = sqrtf(fmaxf(fabsf(v), 1e-8f));
    out[(size_t)n * DD + lane] = acc / den;
}

// ---------------------------------------------------------------- launch ---
extern "C" void kernel_launch(void* const* d_in, const int* in_sizes, int n_in,
                              void* d_out, int out_size, void* d_ws, size_t ws_size,
                              hipStream_t stream) {
    const float* x      = (const float*)d_in[0];  // (12000, 64) f32
    const int*   nei    = (const int*)  d_in[1];  // (12000, 32) int32
    const int*   mask   = (const int*)  d_in[2];  // (12000, 32) int32
    const float* kp     = (const float*)d_in[3];  // (8, 64) f32
    const float* W      = (const float*)d_in[4];  // (8, 64, 64) f32
    const float* b      = (const float*)d_in[5];  // (8, 64) f32
    const float* scales = (const float*)d_in[6];  // (8,) f32
    float*       out    = (float*)d_out;          // (12000, 64) f32

    // workspace layout (floats): [0,512) km ; [512,520) escale ; [1024, 1024+12000*64) F
    const size_t needed = (size_t)(1024 + NPTS * DD) * sizeof(float);
    if (ws_size < needed) return;  // fail loudly (output stays zero)
    float* km     = (float*)d_ws;
    float* escale = km + 512;
    float* F      = km + 1024;

    prep_kernel<<<1, 64, 0, stream>>>(kp, scales, km, escale);
    passA_kernel<<<NPTS / 4, 256, 0, stream>>>(x, W, b, km, escale, F);
    passB_kernel<<<NPTS / 4, 256, 0, stream>>>(F, nei, mask, out);
}

// Round 2
// 70.449 us; speedup vs baseline: 1.1793x; 1.1793x over previous
//
#include <hip/hip_runtime.h>
#include <math.h>

// Problem constants: N=12000, NEI=32, K=8, D=64
#define NPTS 12000
#define NNEI 32
#define KK   8
#define DD   64

#define BLKPTS 24   // points per block (3 rounds of 8)
#define RNDPTS 8    // points per round == KK (one combine point per wave)
#define NBLK   (NPTS / BLKPTS)   // 500

// Pass A structure (round 2): one wave per kernel k. Each lane holds
// W[k][lane][0..63] in 64 VGPRs (loaded once). Per round: 8 x-rows staged in
// LDS; matvec = 16 broadcast ds_read_b128 + 64 VGPR FMAs per point. Cross-k
// softmax/combine through a 16KB LDS xtr buffer; wave w combines point w.

// ---------------------------------------------------------------- prep ----
__global__ void prep_kernel(const float* __restrict__ kp,
                            const float* __restrict__ scales,
                            float* __restrict__ km,
                            float* __restrict__ escale) {
    int l = threadIdx.x;  // 0..63, one wave
    #pragma unroll
    for (int k = 0; k < KK; ++k) {
        float sp = (l == 0) ? 0.0f : kp[k * DD + l];  // kernel_points[:,0] == 0
        float ss = sp * sp;
        #pragma unroll
        for (int off = 32; off > 0; off >>= 1) ss += __shfl_xor(ss, off);
        float nrm = sqrtf(fmaxf(ss, 1e-8f));
        float val = (l == 0) ? coshf(nrm) : -(sinhf(nrm) / nrm) * sp;  // kernels*metric
        km[k * DD + l] = val;
    }
    if (l < KK) escale[l] = expf(scales[l]);
}

// ---------------------------------------------------------------- pass A ---
__launch_bounds__(512)
__global__ void passA_kernel(const float* __restrict__ x,
                             const float* __restrict__ W,
                             const float* __restrict__ b,
                             const float* __restrict__ km,
                             const float* __restrict__ escale,
                             float* __restrict__ F) {
    __shared__ float xlds[RNDPTS][DD];        // 2 KB: staged x rows
    __shared__ float xtr [KK][RNDPTS][DD];    // 16 KB: per-k transformed rows
    __shared__ float disl[KK][RNDPTS];        // 256 B: per-(k,pt) distances

    const int t    = threadIdx.x;
    const int w    = t >> 6;        // wave index == kernel index k
    const int lane = t & 63;
    const int k    = w;

    // per-wave constants
    const float kml = km[k * DD + lane];      // (kernels*metric)[k][lane]
    const float bl  = b [k * DD + lane];
    const float es  = escale[k];

    // W[k][lane][0..63] -> 16 float4 registers (static indexing only)
    float4 Wv[16];
    {
        const float4* Wp = (const float4*)(W + ((size_t)k * DD + lane) * DD);
        #pragma unroll
        for (int i = 0; i < 16; ++i) Wv[i] = Wp[i];
    }

    const int jbase = blockIdx.x * BLKPTS;

    for (int r = 0; r < BLKPTS / RNDPTS; ++r) {
        __syncthreads();  // previous round's combine reads finished
        // stage 8 consecutive x rows = 2 KB contiguous
        if (t < 128) {
            const float4* src = (const float4*)(x + (size_t)(jbase + r * RNDPTS) * DD);
            ((float4*)xlds)[t] = src[t];
        }
        __syncthreads();

        // -------- producer phase: this wave's k for all 8 points --------
        for (int pt = 0; pt < RNDPTS; ++pt) {
            const float xl = xlds[pt][lane];

            // dis[k,pt] = arccosh(clip(<x, km_k>, 1+1e-7))
            float p = xl * kml;
            #pragma unroll
            for (int off = 32; off > 0; off >>= 1) p += __shfl_xor(p, off);
            float nc  = fmaxf(p, 1.0f + 1e-7f);
            float dis = logf(nc + sqrtf(nc * nc - 1.0f));
            if (lane == 0) disl[k][pt] = dis;

            // y_lane = b[k][lane] + W[k][lane][:] . x   (broadcast b128 reads)
            float y = bl;
            const float4* xv4 = (const float4*)xlds[pt];
            #pragma unroll
            for (int d4 = 0; d4 < 16; ++d4) {
                float4 xv = xv4[d4];
                y += Wv[d4].x * xv.x;
                y += Wv[d4].y * xv.y;
                y += Wv[d4].z * xv.z;
                y += Wv[d4].w * xv.w;
            }

            // row stats
            float ysq = (lane == 0) ? 0.0f : y * y;
            #pragma unroll
            for (int off = 32; off > 0; off >>= 1) ysq += __shfl_xor(ysq, off);
            float y0 = __shfl(y, 0);

            float time = es / (1.0f + expf(-y0)) + 1.0001f;
            float sc   = (time * time - 1.0f) / fmaxf(ysq, 1e-8f);
            float s3   = sqrtf(sc);
            xtr[k][pt][lane] = (lane == 0) ? time : y * s3;
        }
        __syncthreads();

        // -------- combine phase: wave w handles point pt == w --------
        {
            const int pt = w;
            float dk[KK];
            #pragma unroll
            for (int q = 0; q < KK; ++q) dk[q] = disl[q][pt];  // broadcast
            float mx = -dk[0];
            #pragma unroll
            for (int q = 1; q < KK; ++q) mx = fmaxf(mx, -dk[q]);
            float wk[KK], sum = 0.0f;
            #pragma unroll
            for (int q = 0; q < KK; ++q) { wk[q] = expf(-dk[q] - mx); sum += wk[q]; }
            float inv = 1.0f / sum;

            float agg = 0.0f;
            #pragma unroll
            for (int q = 0; q < KK; ++q) agg += (wk[q] * inv) * xtr[q][pt][lane];

            float v = (lane == 0) ? -agg * agg : agg * agg;
            #pragma unroll
            for (int off = 32; off > 0; off >>= 1) v += __shfl_xor(v, off);
            float den = sqrtf(fmaxf(fabsf(v), 1e-8f));
            F[(size_t)(jbase + r * RNDPTS + pt) * DD + lane] = agg / den;
        }
    }
}

// ---------------------------------------------------------------- pass B ---
__launch_bounds__(256)
__global__ void passB_kernel(const float* __restrict__ F,
                             const int* __restrict__ nei,
                             const int* __restrict__ mask,
                             float* __restrict__ out) {
    const int t    = threadIdx.x;
    const int wave = t >> 6;
    const int lane = t & 63;
    const int n    = blockIdx.x * 4 + wave;

    float acc = 0.0f;
    #pragma unroll 4
    for (int m = 0; m < NNEI; ++m) {
        int   jm = nei[n * NNEI + m];                 // wave-uniform
        float wgt = (float)mask[n * NNEI + m] + 1e-4f;
        acc += wgt * F[(size_t)jm * DD + lane];       // coalesced 256B row
    }
    float v = (lane == 0) ? -acc * acc : acc * acc;
    #pragma unroll
    for (int off = 32; off > 0; off >>= 1) v += __shfl_xor(v, off);
    float den = sqrtf(fmaxf(fabsf(v), 1e-8f));
    out[(size_t)n * DD + lane] = acc / den;
}

// ---------------------------------------------------------------- launch ---
extern "C" void kernel_launch(void* const* d_in, const int* in_sizes, int n_in,
                              void* d_out, int out_size, void* d_ws, size_t ws_size,
                              hipStream_t stream) {
    const float* x      = (const float*)d_in[0];  // (12000, 64) f32
    const int*   nei    = (const int*)  d_in[1];  // (12000, 32) int32
    const int*   mask   = (const int*)  d_in[2];  // (12000, 32) int32
    const float* kp     = (const float*)d_in[3];  // (8, 64) f32
    const float* W      = (const float*)d_in[4];  // (8, 64, 64) f32
    const float* b      = (const float*)d_in[5];  // (8, 64) f32
    const float* scales = (const float*)d_in[6];  // (8,) f32
    float*       out    = (float*)d_out;          // (12000, 64) f32

    // workspace layout (floats): [0,512) km ; [512,520) escale ; [1024, ...) F
    const size_t needed = (size_t)(1024 + NPTS * DD) * sizeof(float);
    if (ws_size < needed) return;
    float* km     = (float*)d_ws;
    float* escale = km + 512;
    float* F      = km + 1024;

    prep_kernel<<<1, 64, 0, stream>>>(kp, scales, km, escale);
    passA_kernel<<<NBLK, 512, 0, stream>>>(x, W, b, km, escale, F);
    passB_kernel<<<NPTS / 4, 256, 0, stream>>>(F, nei, mask, out);
}

// Round 3
// 49.216 us; speedup vs baseline: 1.6881x; 1.4314x over previous
//
#include <hip/hip_runtime.h>
#include <math.h>

// Problem constants: N=12000, NEI=32, K=8, D=64
#define NPTS 12000
#define NNEI 32
#define KK   8
#define DD   64

// Pass A (round 3): MFMA. One block = 16 points, 8 waves = 8 kernels k.
//   Y_k = X * W_k^T via mfma_f32_16x16x32_bf16 with split-bf16 (hi+lo) fp32
//   emulation (hh + hl + lh products, fp32 accumulate; rel err ~2^-18).
//   A-frag: lane l holds X[pbase + (l&15)][(l>>4)*8 + j (+32*ks)]
//   B-frag: lane l holds W[k][nt*16 + (l&15)][(l>>4)*8 + j (+32*ks)]
//   C/D:    lane l, reg r -> row p=(l>>4)*4+r (point), col o=nt*16+(l&15)  [m89]
//   dis comes free: an extra N-tile with B built from km rows (8 kernels).
// Cross-k exchange of xtr rows through LDS [k][16][65] (pad 65 -> combine
// reads are conflict-free), then wave w combines points {2w, 2w+1}.

typedef __bf16 bf16x8 __attribute__((ext_vector_type(8)));
typedef float  f32x4  __attribute__((ext_vector_type(4)));

#define MFMA16(A, B, C) __builtin_amdgcn_mfma_f32_16x16x32_bf16((A), (B), (C), 0, 0, 0)

__device__ __forceinline__ void pack8(float4 u, float4 v, bf16x8& h, bf16x8& l) {
    float a[8] = {u.x, u.y, u.z, u.w, v.x, v.y, v.z, v.w};
    #pragma unroll
    for (int i = 0; i < 8; ++i) {
        __bf16 hh = (__bf16)a[i];
        h[i] = hh;
        l[i] = (__bf16)(a[i] - (float)hh);
    }
}

// ---------------------------------------------------------------- prep ----
__global__ void prep_kernel(const float* __restrict__ kp,
                            const float* __restrict__ scales,
                            float* __restrict__ km,
                            float* __restrict__ escale) {
    int l = threadIdx.x;  // 0..63, one wave
    #pragma unroll
    for (int k = 0; k < KK; ++k) {
        float sp = (l == 0) ? 0.0f : kp[k * DD + l];  // kernel_points[:,0] == 0
        float ss = sp * sp;
        #pragma unroll
        for (int off = 32; off > 0; off >>= 1) ss += __shfl_xor(ss, off);
        float nrm = sqrtf(fmaxf(ss, 1e-8f));
        float val = (l == 0) ? coshf(nrm) : -(sinhf(nrm) / nrm) * sp;  // kernels*metric
        km[k * DD + l] = val;
    }
    if (l < KK) escale[l] = expf(scales[l]);
}

// ---------------------------------------------------------------- pass A ---
__launch_bounds__(512)
__global__ void passA_kernel(const float* __restrict__ x,
                             const float* __restrict__ W,
                             const float* __restrict__ b,
                             const float* __restrict__ km,
                             const float* __restrict__ escale,
                             float* __restrict__ F) {
    __shared__ float xtr[KK][16][65];   // [k][point][o], pad 65 -> combine conflict-free
    __shared__ float disl[16][12];      // [point][k]

    const int t     = threadIdx.x;
    const int k     = t >> 6;           // wave index == kernel index
    const int lane  = t & 63;
    const int c     = lane & 15;
    const int g     = lane >> 4;
    const int pbase = blockIdx.x * 16;

    // ---- W_k fragments (hi/lo), loaded once per block ----
    bf16x8 Wh[4][2], Wl[4][2];
    #pragma unroll
    for (int nt = 0; nt < 4; ++nt)
        #pragma unroll
        for (int ks = 0; ks < 2; ++ks) {
            const float* wr = W + ((size_t)k * 64 + nt * 16 + c) * 64 + ks * 32 + g * 8;
            pack8(*(const float4*)wr, *(const float4*)(wr + 4), Wh[nt][ks], Wl[nt][ks]);
        }
    // km fragments (rows 8..15 padded with zeros)
    bf16x8 Mh[2], Ml[2];
    #pragma unroll
    for (int ks = 0; ks < 2; ++ks) {
        float4 u = {0.f, 0.f, 0.f, 0.f}, v = {0.f, 0.f, 0.f, 0.f};
        if (c < 8) {
            const float* mr = km + (size_t)c * 64 + ks * 32 + g * 8;
            u = *(const float4*)mr; v = *(const float4*)(mr + 4);
        }
        pack8(u, v, Mh[ks], Ml[ks]);
    }
    const float es = escale[k];
    float bnt[4];
    #pragma unroll
    for (int nt = 0; nt < 4; ++nt) bnt[nt] = b[k * 64 + nt * 16 + c];

    // ---- A fragments: this block's 16 x-rows ----
    bf16x8 Ah[2], Al[2];
    {
        const float* xr = x + (size_t)(pbase + c) * 64 + g * 8;
        pack8(*(const float4*)(xr +  0), *(const float4*)(xr +  4), Ah[0], Al[0]);
        pack8(*(const float4*)(xr + 32), *(const float4*)(xr + 36), Ah[1], Al[1]);
    }

    // ---- MFMAs: Y (4 N-tiles) + inner (1 N-tile, all 8 k at once) ----
    f32x4 accY[4];
    #pragma unroll
    for (int nt = 0; nt < 4; ++nt) accY[nt] = (f32x4){0.f, 0.f, 0.f, 0.f};
    f32x4 accI = (f32x4){0.f, 0.f, 0.f, 0.f};
    #pragma unroll
    for (int ks = 0; ks < 2; ++ks) {
        #pragma unroll
        for (int nt = 0; nt < 4; ++nt) {
            accY[nt] = MFMA16(Ah[ks], Wh[nt][ks], accY[nt]);
            accY[nt] = MFMA16(Ah[ks], Wl[nt][ks], accY[nt]);
            accY[nt] = MFMA16(Al[ks], Wh[nt][ks], accY[nt]);
        }
        accI = MFMA16(Ah[ks], Mh[ks], accI);
        accI = MFMA16(Ah[ks], Ml[ks], accI);
        accI = MFMA16(Al[ks], Mh[ks], accI);
    }

    // ---- epilogue: per-point stats on the C layout ----
    float yv[4][4];   // [nt][r]
    float sall[4];    // [r] = sum over all o of y^2
    #pragma unroll
    for (int r = 0; r < 4; ++r) {
        float s = 0.f;
        #pragma unroll
        for (int nt = 0; nt < 4; ++nt) {
            float y = accY[nt][r] + bnt[nt];
            yv[nt][r] = y;
            s += y * y;
        }
        sall[r] = s;
    }
    #pragma unroll
    for (int m = 1; m <= 8; m <<= 1) {
        #pragma unroll
        for (int r = 0; r < 4; ++r) sall[r] += __shfl_xor(sall[r], m);
    }
    float y0[4];
    #pragma unroll
    for (int r = 0; r < 4; ++r) y0[r] = __shfl(yv[0][r], lane & 48);  // col 0 of group

    #pragma unroll
    for (int r = 0; r < 4; ++r) {
        const int p = g * 4 + r;
        float nar2 = fmaxf(sall[r] - y0[r] * y0[r], 1e-8f);
        float time = es / (1.0f + expf(-y0[r])) + 1.0001f;
        float s3   = sqrtf((time * time - 1.0f) / nar2);
        #pragma unroll
        for (int nt = 0; nt < 4; ++nt) {
            float v = yv[nt][r] * s3;
            if (nt == 0 && c == 0) v = time;
            xtr[k][p][nt * 16 + c] = v;
        }
    }

    // dis for all 8 kernels (wave 0's accI tile has them as cols 0..7)
    if (k == 0) {
        #pragma unroll
        for (int r = 0; r < 4; ++r) {
            float nc  = fmaxf(accI[r], 1.0f + 1e-7f);
            float dis = logf(nc + sqrtf(nc * nc - 1.0f));   // arccosh
            if (c < 8) disl[g * 4 + r][c] = dis;
        }
    }
    __syncthreads();

    // ---- combine: wave w handles points {2w, 2w+1} ----
    #pragma unroll
    for (int pi = 0; pi < 2; ++pi) {
        const int p = k * 2 + pi;
        float dk[KK];
        #pragma unroll
        for (int q = 0; q < KK; ++q) dk[q] = disl[p][q];     // broadcast reads
        float mx = -dk[0];
        #pragma unroll
        for (int q = 1; q < KK; ++q) mx = fmaxf(mx, -dk[q]);
        float wk[KK], sum = 0.f;
        #pragma unroll
        for (int q = 0; q < KK; ++q) { wk[q] = expf(-dk[q] - mx); sum += wk[q]; }
        float inv = 1.0f / sum;

        float agg = 0.f;
        #pragma unroll
        for (int q = 0; q < KK; ++q) agg += (wk[q] * inv) * xtr[q][p][lane];

        float vv = (lane == 0) ? -agg * agg : agg * agg;
        #pragma unroll
        for (int m = 32; m > 0; m >>= 1) vv += __shfl_xor(vv, m);
        float den = sqrtf(fmaxf(fabsf(vv), 1e-8f));
        F[(size_t)(pbase + p) * DD + lane] = agg / den;
    }
}

// ---------------------------------------------------------------- pass B ---
// One wave per n. lane = (m-quad g, col-quad c): float4 gather of F rows.
__launch_bounds__(256)
__global__ void passB_kernel(const float* __restrict__ F,
                             const int* __restrict__ nei,
                             const int* __restrict__ mask,
                             float* __restrict__ out) {
    const int t    = threadIdx.x;
    const int wave = t >> 6;
    const int lane = t & 63;
    const int c    = lane & 15;   // col quad: o = 4c..4c+3
    const int g    = lane >> 4;   // m sub-index
    const int n    = blockIdx.x * 4 + wave;

    const float4* F4 = (const float4*)F;
    float4 acc = {0.f, 0.f, 0.f, 0.f};
    #pragma unroll
    for (int mq = 0; mq < 8; ++mq) {
        int   m   = mq * 4 + g;
        int   j   = nei[n * NNEI + m];
        float wgt = (float)mask[n * NNEI + m] + 1e-4f;
        float4 v  = F4[(size_t)j * 16 + c];
        acc.x += wgt * v.x; acc.y += wgt * v.y;
        acc.z += wgt * v.z; acc.w += wgt * v.w;
    }
    // reduce over the 4 m-subgroups (lanes xor 16, 32)
    #pragma unroll
    for (int m = 16; m <= 32; m <<= 1) {
        acc.x += __shfl_xor(acc.x, m); acc.y += __shfl_xor(acc.y, m);
        acc.z += __shfl_xor(acc.z, m); acc.w += __shfl_xor(acc.w, m);
    }
    // lorentz inner: minus sign on o==0 (lane c==0, component .x)
    float s = acc.x * acc.x + acc.y * acc.y + acc.z * acc.z + acc.w * acc.w;
    if (c == 0) s -= 2.0f * acc.x * acc.x;
    #pragma unroll
    for (int m = 1; m <= 8; m <<= 1) s += __shfl_xor(s, m);
    float den = sqrtf(fmaxf(fabsf(s), 1e-8f));
    if (g == 0) {
        float4 r = {acc.x / den, acc.y / den, acc.z / den, acc.w / den};
        ((float4*)out)[(size_t)n * 16 + c] = r;
    }
}

// ---------------------------------------------------------------- launch ---
extern "C" void kernel_launch(void* const* d_in, const int* in_sizes, int n_in,
                              void* d_out, int out_size, void* d_ws, size_t ws_size,
                              hipStream_t stream) {
    const float* x      = (const float*)d_in[0];  // (12000, 64) f32
    const int*   nei    = (const int*)  d_in[1];  // (12000, 32) int32
    const int*   mask   = (const int*)  d_in[2];  // (12000, 32) int32
    const float* kp     = (const float*)d_in[3];  // (8, 64) f32
    const float* W      = (const float*)d_in[4];  // (8, 64, 64) f32
    const float* b      = (const float*)d_in[5];  // (8, 64) f32
    const float* scales = (const float*)d_in[6];  // (8,) f32
    float*       out    = (float*)d_out;          // (12000, 64) f32

    // workspace layout (floats): [0,512) km ; [512,520) escale ; [1024, ...) F
    const size_t needed = (size_t)(1024 + NPTS * DD) * sizeof(float);
    if (ws_size < needed) return;
    float* km     = (float*)d_ws;
    float* escale = km + 512;
    float* F      = km + 1024;

    prep_kernel<<<1, 64, 0, stream>>>(kp, scales, km, escale);
    passA_kernel<<<NPTS / 16, 512, 0, stream>>>(x, W, b, km, escale, F);
    passB_kernel<<<NPTS / 4, 256, 0, stream>>>(F, nei, mask, out);
}